// Round 10
// baseline (208.042 us; speedup 1.0000x reference)
//
#include <hip/hip_runtime.h>
#include <hip/hip_bf16.h>

// Fused hyperbolic MLP forward.
// Identity: logmap0(proj(expmap0(u))) == clip_norm(u, A), A = atanh(0.999).
// Classifier: res = min(tanh(||v||),0.999)*unit(v), v = z2@Wc^T (scale-exact).
// Layout: SWAPPED mfma operands -> D[feature][batch]; lane holds 16 features of
// 4 batch rows => per-row reductions are 16 local FMA + 2 shfls (x^16,x^32).
// R10: RE-GREEN. Byte-exact copy of the R3 kernel that passed (206us,
// absmax 0.0156) after 5 failed structural variants. Only addition:
// s_setprio(1/0) around the MFMA cluster (scheduler hint, zero correctness
// risk). No sync-structure changes.

typedef __bf16 bfrag __attribute__((ext_vector_type(8)));   // MFMA A/B (4 VGPR)
typedef __bf16 bf4   __attribute__((ext_vector_type(4)));
typedef float  ffrag __attribute__((ext_vector_type(4)));   // MFMA C/D

#define ACLIP 3.8002012f   // atanh(0.999)

__device__ __forceinline__ float tanh_fast(float x) {
  float ax = fabsf(x);
  float e  = __expf(2.0f * ax);
  float t  = 1.0f - __fdividef(2.0f, e + 1.0f);
  return copysignf(t, x);
}

// async 16B global -> LDS (DMA, no VGPR round-trip)
__device__ __forceinline__ void gl_lds16(const __bf16* g, __bf16* l) {
  __builtin_amdgcn_global_load_lds(
      (const __attribute__((address_space(1))) void*)g,
      (__attribute__((address_space(3))) void*)l, 16, 0, 0);
}
// stage one 16 KiB k-slice (1024 slots x 16B) with 256 threads: 4 issues/thread
__device__ __forceinline__ void stage_slice(const __bf16* src, __bf16* dst, int tid) {
#pragma unroll
  for (int i = 0; i < 4; ++i)
    gl_lds16(src + (i * 256 + tid) * 8, dst + (i * 256 + tid) * 8);
}
__device__ __forceinline__ void stage_wc(const __bf16* src, __bf16* dst, int tid) {
#pragma unroll
  for (int i = 0; i < 2; ++i)
    gl_lds16(src + (i * 256 + tid) * 8, dst + (i * 256 + tid) * 8);
}

// ---------------------------------------------------------------------------
// prep: reorder W1/W2/Wc (f32 [out][in]) into bf16 MFMA fragment order:
// slot(ks, nt, lane) holds W[nt*16 + (lane&15)][ks*32 + (lane>>4)*8 .. +7]
// W1 slices 0-7 (elem 0), W2 slices 8-15 (elem 65536), Wc at 131072.
// ---------------------------------------------------------------------------
__global__ void prep_kernel(const float* __restrict__ W1, const float* __restrict__ W2,
                            const float* __restrict__ Wc, __bf16* __restrict__ wsb) {
  int g = blockIdx.x * 256 + threadIdx.x;   // 0..16895
  const float* src; int s, base;
  if (g < 8192)        { src = W1; s = g;         base = 0;      }
  else if (g < 16384)  { src = W2; s = g - 8192;  base = 65536;  }
  else                 { src = Wc; s = g - 16384; base = 131072; }
  int l = s & 63, t = s >> 6;
  int nt, ks;
  if (g < 16384) { nt = t & 15; ks = t >> 4; }
  else           { nt = 0;      ks = t;      }
  int row  = nt * 16 + (l & 15);
  int col0 = ks * 32 + (l >> 4) * 8;
  bfrag v;
#pragma unroll
  for (int j = 0; j < 8; ++j) v[j] = (__bf16)src[row * 256 + col0 + j];
  *(bfrag*)(wsb + base + s * 8) = v;
}

// ---------------------------------------------------------------------------
// fused main: 64 rows/block, 4 waves; wave w owns features w*64..w*64+63 for
// all 64 batch rows (acc[ft][bt]). A-tile (X / y, bf16) XOR-swizzled in LDS;
// W double-buffered via global_load_lds (proven path), 1 barrier per k-step.
// ---------------------------------------------------------------------------
__global__ __launch_bounds__(256, 2) void fused_kernel(
    const float* __restrict__ x, const float* __restrict__ b1,
    const float* __restrict__ b2, const float* __restrict__ bc,
    const __bf16* __restrict__ wsb, float* __restrict__ out) {
  __shared__ __align__(16) __bf16 At[64 * 256];   // 32 KB, 512 B/row, swizzled
  __shared__ __align__(16) __bf16 Bt[2][8192];    // 2 x 16 KB W k-slices
  __shared__ float partX[64][4];
  __shared__ float pE1[64][4];
  __shared__ float pE2[64][4];

  const int tid  = threadIdx.x;
  const int w    = tid >> 6;
  const int lane = tid & 63;
  const int lrow = lane & 15;
  const int lgrp = lane >> 4;
  const int swz  = (lrow & 7) << 4;
  const long long rowg = (long long)blockIdx.x * 64;

  // ---- prologue: x loads (HBM) + first W slice (L2), raw bf16 At, partial norms
  float4 xv[16];
#pragma unroll
  for (int rr = 0; rr < 16; ++rr)
    xv[rr] = *(const float4*)(x + (rowg + w * 16 + rr) * 256 + lane * 4);
  stage_slice(wsb, Bt[0], tid);

  float ss[16];
#pragma unroll
  for (int rr = 0; rr < 16; ++rr) {
    int row = w * 16 + rr;
    bf4 z;
    z[0] = (__bf16)xv[rr].x; z[1] = (__bf16)xv[rr].y;
    z[2] = (__bf16)xv[rr].z; z[3] = (__bf16)xv[rr].w;
    *(bf4*)((char*)At + row * 512 + ((lane * 8) ^ ((row & 7) << 4))) = z;
    ss[rr] = xv[rr].x * xv[rr].x + xv[rr].y * xv[rr].y +
             xv[rr].z * xv[rr].z + xv[rr].w * xv[rr].w;
  }
#pragma unroll
  for (int m = 1; m <= 8; m <<= 1)
#pragma unroll
    for (int rr = 0; rr < 16; ++rr) ss[rr] += __shfl_xor(ss[rr], m);
  if (lrow == 0) {   // lanes 0,16,32,48: group-partials for the wave's 16 rows
#pragma unroll
    for (int rr = 0; rr < 16; ++rr) partX[w * 16 + rr][lgrp] = ss[rr];
  }
  __syncthreads();   // At + partX visible; Bt[0] DMA drained

  ffrag acc[4][4];   // [ft][bt]

#pragma unroll
  for (int st = 0; st < 2; ++st) {
#pragma unroll
    for (int ft = 0; ft < 4; ++ft)
#pragma unroll
      for (int bt = 0; bt < 4; ++bt) acc[ft][bt] = (ffrag){0.f, 0.f, 0.f, 0.f};

#pragma unroll
    for (int j = 0; j < 8; ++j) {
      const int t = st * 8 + j;
      if (t < 15) stage_slice(wsb + (t + 1) * 8192, Bt[(t + 1) & 1], tid);
      else        stage_wc(wsb + 131072, Bt[0], tid);   // Wc into Bt[0]
      const __bf16* cb = Bt[t & 1];
      bfrag wf[4], xf[4];
#pragma unroll
      for (int ft = 0; ft < 4; ++ft)
        wf[ft] = *(const bfrag*)(cb + ((w * 4 + ft) * 64 + lane) * 8);
#pragma unroll
      for (int bt = 0; bt < 4; ++bt)
        xf[bt] = *(const bfrag*)((const char*)At + (bt * 16 + lrow) * 512 +
                                 ((j * 64 + lgrp * 16) ^ swz));
      __builtin_amdgcn_s_setprio(1);
#pragma unroll
      for (int ft = 0; ft < 4; ++ft)
#pragma unroll
        for (int bt = 0; bt < 4; ++bt)
          acc[ft][bt] = __builtin_amdgcn_mfma_f32_16x16x32_bf16(
              wf[ft], xf[bt], acc[ft][bt], 0, 0, 0);
      __builtin_amdgcn_s_setprio(0);
      __syncthreads();   // drains next-slice DMA; protects buffer reuse
    }

    // ---- epilogue: u = fr*acc + bias; clip_norm; tanh; clip_norm; y -> At ----
    const float* bias = st ? b2 : b1;
    float bb[4][4];
#pragma unroll
    for (int ft = 0; ft < 4; ++ft)
#pragma unroll
      for (int r = 0; r < 4; ++r) bb[ft][r] = bias[w * 64 + ft * 16 + lgrp * 4 + r];

    float f0[4];
    if (st == 0) {
#pragma unroll
      for (int bt = 0; bt < 4; ++bt) {
        const float4 p = *(const float4*)partX[bt * 16 + lrow];
        float s = p.x + p.y + p.z + p.w;
        f0[bt] = fminf(1.0f, ACLIP * rsqrtf(fmaxf(s, 1e-30f)));
      }
    } else {
#pragma unroll
      for (int bt = 0; bt < 4; ++bt) f0[bt] = 1.0f;
    }

    float s1[4] = {0.f, 0.f, 0.f, 0.f};
#pragma unroll
    for (int ft = 0; ft < 4; ++ft)
#pragma unroll
      for (int bt = 0; bt < 4; ++bt)
#pragma unroll
        for (int r = 0; r < 4; ++r) {
          float u = acc[ft][bt][r] * f0[bt] + bb[ft][r];
          acc[ft][bt][r] = u;
          s1[bt] += u * u;
        }
#pragma unroll
    for (int bt = 0; bt < 4; ++bt) {
      s1[bt] += __shfl_xor(s1[bt], 16);
      s1[bt] += __shfl_xor(s1[bt], 32);
    }
    if (lgrp == 0) {
#pragma unroll
      for (int bt = 0; bt < 4; ++bt) pE1[bt * 16 + lrow][w] = s1[bt];
    }
    __syncthreads();

    float f1[4];
#pragma unroll
    for (int bt = 0; bt < 4; ++bt) {
      const float4 p = *(const float4*)pE1[bt * 16 + lrow];
      float s = p.x + p.y + p.z + p.w;
      f1[bt] = fminf(1.0f, ACLIP * rsqrtf(fmaxf(s, 1e-30f)));
    }
    float s2[4] = {0.f, 0.f, 0.f, 0.f};
#pragma unroll
    for (int ft = 0; ft < 4; ++ft)
#pragma unroll
      for (int bt = 0; bt < 4; ++bt)
#pragma unroll
        for (int r = 0; r < 4; ++r) {
          float zz = tanh_fast(acc[ft][bt][r] * f1[bt]);
          acc[ft][bt][r] = zz;
          s2[bt] += zz * zz;
        }
#pragma unroll
    for (int bt = 0; bt < 4; ++bt) {
      s2[bt] += __shfl_xor(s2[bt], 16);
      s2[bt] += __shfl_xor(s2[bt], 32);
    }
    if (lgrp == 0) {
#pragma unroll
      for (int bt = 0; bt < 4; ++bt) pE2[bt * 16 + lrow][w] = s2[bt];
    }
    __syncthreads();

#pragma unroll
    for (int bt = 0; bt < 4; ++bt) {
      const float4 p = *(const float4*)pE2[bt * 16 + lrow];
      float s = p.x + p.y + p.z + p.w;
      float f2 = fminf(1.0f, ACLIP * rsqrtf(fmaxf(s, 1e-30f)));
      int row = bt * 16 + lrow;
#pragma unroll
      for (int ft = 0; ft < 4; ++ft) {
        bf4 yv;
#pragma unroll
        for (int r = 0; r < 4; ++r) yv[r] = (__bf16)(acc[ft][bt][r] * f2);
        *(bf4*)((char*)At + row * 512 +
                (((w * 64 + ft * 16 + lgrp * 4) * 2) ^ ((row & 7) << 4))) = yv;
      }
    }
    __syncthreads();   // y visible for next stage / classifier
  }

  // ---- classifier: v = y2 @ Wc^T (16 classes), mobius epilogue ----
  // lane: batch = w*16+lrow, classes lgrp*4+r (reduce over lgrp: 2 shfls)
  float bcv[4];
#pragma unroll
  for (int r = 0; r < 4; ++r) bcv[r] = bc[lgrp * 4 + r];
  float pp = bcv[0]*bcv[0] + bcv[1]*bcv[1] + bcv[2]*bcv[2] + bcv[3]*bcv[3];
  pp += __shfl_xor(pp, 16); pp += __shfl_xor(pp, 32);
  float nb = sqrtf(fmaxf(pp, 1e-30f));
  float tnb = tanh_fast(nb);
  float pratio = (nb < 1e-4f) ? 1.0f : __fdividef(fminf(tnb, 0.999f), nb);
  float pj[4];
#pragma unroll
  for (int r = 0; r < 4; ++r) pj[r] = bcv[r] * pratio;
  float p2 = pratio * pratio * pp;

  ffrag c2 = (ffrag){0.f, 0.f, 0.f, 0.f};
#pragma unroll
  for (int ks = 0; ks < 8; ++ks) {
    bfrag a = *(const bfrag*)(Bt[0] + (ks * 64 + lane) * 8);
    bfrag b = *(const bfrag*)((const char*)At + (w * 16 + lrow) * 512 +
                              ((ks * 64 + lgrp * 16) ^ swz));
    c2 = __builtin_amdgcn_mfma_f32_16x16x32_bf16(a, b, c2, 0, 0, 0);
  }
  float g2 = c2[0]*c2[0] + c2[1]*c2[1] + c2[2]*c2[2] + c2[3]*c2[3];
  g2 += __shfl_xor(g2, 16); g2 += __shfl_xor(g2, 32);
  float gn = sqrtf(fmaxf(g2, 1e-30f));
  float tg = tanh_fast(gn);
  float rn = fminf(tg, 0.999f);
  float ratio = (gn < 1e-4f) ? 1.0f : __fdividef(rn, gn);
  float x2 = ratio * ratio * g2;
  float xj[4], r2j[4];
  float xy = 0.f;
#pragma unroll
  for (int r = 0; r < 4; ++r) { xj[r] = c2[r] * ratio; xy += xj[r] * pj[r]; }
  xy += __shfl_xor(xy, 16); xy += __shfl_xor(xy, 32);
  float na = 1.f + 2.f * xy + p2;
  float de = fmaxf(1.f + 2.f * xy + x2 * p2, 1e-15f);
  float rde = __fdividef(1.0f, de);
  float n2s = 0.f;
#pragma unroll
  for (int r = 0; r < 4; ++r) {
    r2j[r] = (na * xj[r] + (1.f - x2) * pj[r]) * rde;
    n2s += r2j[r] * r2j[r];
  }
  n2s += __shfl_xor(n2s, 16); n2s += __shfl_xor(n2s, 32);
  float n2 = sqrtf(fmaxf(n2s, 1e-30f));
  float pscl = (n2 > 0.999f) ? (0.999f / n2) : 1.0f;
  float n3 = fminf(n2, 0.999f);
  float lfac = (n3 < 1e-4f)
                   ? 1.0f
                   : __fdividef(0.5f * __logf((1.f + n3) / (1.f - n3)), n3);
  float* oT = (float*)Bt[1];   // reuse as [64][17] f32 staging (4.4 KB)
#pragma unroll
  for (int r = 0; r < 4; ++r) {
    float lg = r2j[r] * pscl * lfac;
    float sp = (lg > 20.f) ? lg : log1pf(__expf(lg));
    oT[(w * 16 + lrow) * 17 + lgrp * 4 + r] = sp;
  }
  __syncthreads();
  {
    int row = tid >> 2, c = (tid & 3) * 4;
    float4 o;
    o.x = oT[row * 17 + c];     o.y = oT[row * 17 + c + 1];
    o.z = oT[row * 17 + c + 2]; o.w = oT[row * 17 + c + 3];
    *(float4*)(out + (rowg + row) * 16 + c) = o;
  }
}

extern "C" void kernel_launch(void* const* d_in, const int* in_sizes, int n_in,
                              void* d_out, int out_size, void* d_ws, size_t ws_size,
                              hipStream_t stream) {
  (void)in_sizes; (void)n_in; (void)out_size; (void)ws_size;
  const float* x  = (const float*)d_in[0];
  const float* W1 = (const float*)d_in[1];
  const float* b1 = (const float*)d_in[2];
  const float* W2 = (const float*)d_in[3];
  const float* b2 = (const float*)d_in[4];
  const float* Wc = (const float*)d_in[5];
  const float* bc = (const float*)d_in[6];
  __bf16* wsb = (__bf16*)d_ws;          // needs 270336 B

  prep_kernel<<<66, 256, 0, stream>>>(W1, W2, Wc, wsb);
  fused_kernel<<<4096, 256, 0, stream>>>(x, b1, b2, bc, wsb, (float*)d_out);
}

// Round 11
// 181.991 us; speedup vs baseline: 1.1431x; 1.1431x over previous
//
#include <hip/hip_runtime.h>
#include <hip/hip_bf16.h>

// Fused hyperbolic MLP forward.
// Identity: logmap0(proj(expmap0(u))) == clip_norm(u, A), A = atanh(0.999).
// Classifier: res = min(tanh(||v||),0.999)*unit(v), v = z2@Wc^T (scale-exact).
// Layout: SWAPPED mfma operands -> D[feature][batch]; lane holds 16 features of
// 4 batch rows => per-row reductions are 16 local FMA + 2 shfls (x^16,x^32).
// R11: proven R10 kernel + pure-VALU cuts only (no sync/layout changes):
//   tanh = fma(-2, rcp(exp(2x)+1), 1)  [5 inst vs 10; valid for all x incl inf]
//   bias loads vectorized to float4.

typedef __bf16 bfrag __attribute__((ext_vector_type(8)));   // MFMA A/B (4 VGPR)
typedef __bf16 bf4   __attribute__((ext_vector_type(4)));
typedef float  ffrag __attribute__((ext_vector_type(4)));   // MFMA C/D

#define ACLIP 3.8002012f   // atanh(0.999)

__device__ __forceinline__ float tanh_fast(float x) {
  // tanh(x) = 1 - 2/(e^{2x}+1); handles +-inf gracefully (->+-1).
  float e = __expf(2.0f * x);
  float r = __builtin_amdgcn_rcpf(e + 1.0f);
  return fmaf(-2.0f, r, 1.0f);
}

// async 16B global -> LDS (DMA, no VGPR round-trip)
__device__ __forceinline__ void gl_lds16(const __bf16* g, __bf16* l) {
  __builtin_amdgcn_global_load_lds(
      (const __attribute__((address_space(1))) void*)g,
      (__attribute__((address_space(3))) void*)l, 16, 0, 0);
}
// stage one 16 KiB k-slice (1024 slots x 16B) with 256 threads: 4 issues/thread
__device__ __forceinline__ void stage_slice(const __bf16* src, __bf16* dst, int tid) {
#pragma unroll
  for (int i = 0; i < 4; ++i)
    gl_lds16(src + (i * 256 + tid) * 8, dst + (i * 256 + tid) * 8);
}
__device__ __forceinline__ void stage_wc(const __bf16* src, __bf16* dst, int tid) {
#pragma unroll
  for (int i = 0; i < 2; ++i)
    gl_lds16(src + (i * 256 + tid) * 8, dst + (i * 256 + tid) * 8);
}

// ---------------------------------------------------------------------------
// prep: reorder W1/W2/Wc (f32 [out][in]) into bf16 MFMA fragment order:
// slot(ks, nt, lane) holds W[nt*16 + (lane&15)][ks*32 + (lane>>4)*8 .. +7]
// W1 slices 0-7 (elem 0), W2 slices 8-15 (elem 65536), Wc at 131072.
// ---------------------------------------------------------------------------
__global__ void prep_kernel(const float* __restrict__ W1, const float* __restrict__ W2,
                            const float* __restrict__ Wc, __bf16* __restrict__ wsb) {
  int g = blockIdx.x * 256 + threadIdx.x;   // 0..16895
  const float* src; int s, base;
  if (g < 8192)        { src = W1; s = g;         base = 0;      }
  else if (g < 16384)  { src = W2; s = g - 8192;  base = 65536;  }
  else                 { src = Wc; s = g - 16384; base = 131072; }
  int l = s & 63, t = s >> 6;
  int nt, ks;
  if (g < 16384) { nt = t & 15; ks = t >> 4; }
  else           { nt = 0;      ks = t;      }
  int row  = nt * 16 + (l & 15);
  int col0 = ks * 32 + (l >> 4) * 8;
  bfrag v;
#pragma unroll
  for (int j = 0; j < 8; ++j) v[j] = (__bf16)src[row * 256 + col0 + j];
  *(bfrag*)(wsb + base + s * 8) = v;
}

// ---------------------------------------------------------------------------
// fused main: 64 rows/block, 4 waves; wave w owns features w*64..w*64+63 for
// all 64 batch rows (acc[ft][bt]). A-tile (X / y, bf16) XOR-swizzled in LDS;
// W double-buffered via global_load_lds (proven path), 1 barrier per k-step.
// ---------------------------------------------------------------------------
__global__ __launch_bounds__(256, 2) void fused_kernel(
    const float* __restrict__ x, const float* __restrict__ b1,
    const float* __restrict__ b2, const float* __restrict__ bc,
    const __bf16* __restrict__ wsb, float* __restrict__ out) {
  __shared__ __align__(16) __bf16 At[64 * 256];   // 32 KB, 512 B/row, swizzled
  __shared__ __align__(16) __bf16 Bt[2][8192];    // 2 x 16 KB W k-slices
  __shared__ float partX[64][4];
  __shared__ float pE1[64][4];
  __shared__ float pE2[64][4];

  const int tid  = threadIdx.x;
  const int w    = tid >> 6;
  const int lane = tid & 63;
  const int lrow = lane & 15;
  const int lgrp = lane >> 4;
  const int swz  = (lrow & 7) << 4;
  const long long rowg = (long long)blockIdx.x * 64;

  // ---- prologue: x loads (HBM) + first W slice (L2), raw bf16 At, partial norms
  float4 xv[16];
#pragma unroll
  for (int rr = 0; rr < 16; ++rr)
    xv[rr] = *(const float4*)(x + (rowg + w * 16 + rr) * 256 + lane * 4);
  stage_slice(wsb, Bt[0], tid);

  float ss[16];
#pragma unroll
  for (int rr = 0; rr < 16; ++rr) {
    int row = w * 16 + rr;
    bf4 z;
    z[0] = (__bf16)xv[rr].x; z[1] = (__bf16)xv[rr].y;
    z[2] = (__bf16)xv[rr].z; z[3] = (__bf16)xv[rr].w;
    *(bf4*)((char*)At + row * 512 + ((lane * 8) ^ ((row & 7) << 4))) = z;
    ss[rr] = xv[rr].x * xv[rr].x + xv[rr].y * xv[rr].y +
             xv[rr].z * xv[rr].z + xv[rr].w * xv[rr].w;
  }
#pragma unroll
  for (int m = 1; m <= 8; m <<= 1)
#pragma unroll
    for (int rr = 0; rr < 16; ++rr) ss[rr] += __shfl_xor(ss[rr], m);
  if (lrow == 0) {   // lanes 0,16,32,48: group-partials for the wave's 16 rows
#pragma unroll
    for (int rr = 0; rr < 16; ++rr) partX[w * 16 + rr][lgrp] = ss[rr];
  }
  __syncthreads();   // At + partX visible; Bt[0] DMA drained

  ffrag acc[4][4];   // [ft][bt]

#pragma unroll
  for (int st = 0; st < 2; ++st) {
#pragma unroll
    for (int ft = 0; ft < 4; ++ft)
#pragma unroll
      for (int bt = 0; bt < 4; ++bt) acc[ft][bt] = (ffrag){0.f, 0.f, 0.f, 0.f};

#pragma unroll
    for (int j = 0; j < 8; ++j) {
      const int t = st * 8 + j;
      if (t < 15) stage_slice(wsb + (t + 1) * 8192, Bt[(t + 1) & 1], tid);
      else        stage_wc(wsb + 131072, Bt[0], tid);   // Wc into Bt[0]
      const __bf16* cb = Bt[t & 1];
      bfrag wf[4], xf[4];
#pragma unroll
      for (int ft = 0; ft < 4; ++ft)
        wf[ft] = *(const bfrag*)(cb + ((w * 4 + ft) * 64 + lane) * 8);
#pragma unroll
      for (int bt = 0; bt < 4; ++bt)
        xf[bt] = *(const bfrag*)((const char*)At + (bt * 16 + lrow) * 512 +
                                 ((j * 64 + lgrp * 16) ^ swz));
      __builtin_amdgcn_s_setprio(1);
#pragma unroll
      for (int ft = 0; ft < 4; ++ft)
#pragma unroll
        for (int bt = 0; bt < 4; ++bt)
          acc[ft][bt] = __builtin_amdgcn_mfma_f32_16x16x32_bf16(
              wf[ft], xf[bt], acc[ft][bt], 0, 0, 0);
      __builtin_amdgcn_s_setprio(0);
      __syncthreads();   // drains next-slice DMA; protects buffer reuse
    }

    // ---- epilogue: u = fr*acc + bias; clip_norm; tanh; clip_norm; y -> At ----
    const float* bias = st ? b2 : b1;
    float bb[4][4];
#pragma unroll
    for (int ft = 0; ft < 4; ++ft) {
      const float4 bv = *(const float4*)(bias + w * 64 + ft * 16 + lgrp * 4);
      bb[ft][0] = bv.x; bb[ft][1] = bv.y; bb[ft][2] = bv.z; bb[ft][3] = bv.w;
    }

    float f0[4];
    if (st == 0) {
#pragma unroll
      for (int bt = 0; bt < 4; ++bt) {
        const float4 p = *(const float4*)partX[bt * 16 + lrow];
        float s = p.x + p.y + p.z + p.w;
        f0[bt] = fminf(1.0f, ACLIP * rsqrtf(fmaxf(s, 1e-30f)));
      }
    } else {
#pragma unroll
      for (int bt = 0; bt < 4; ++bt) f0[bt] = 1.0f;
    }

    float s1[4] = {0.f, 0.f, 0.f, 0.f};
#pragma unroll
    for (int ft = 0; ft < 4; ++ft)
#pragma unroll
      for (int bt = 0; bt < 4; ++bt)
#pragma unroll
        for (int r = 0; r < 4; ++r) {
          float u = acc[ft][bt][r] * f0[bt] + bb[ft][r];
          acc[ft][bt][r] = u;
          s1[bt] += u * u;
        }
#pragma unroll
    for (int bt = 0; bt < 4; ++bt) {
      s1[bt] += __shfl_xor(s1[bt], 16);
      s1[bt] += __shfl_xor(s1[bt], 32);
    }
    if (lgrp == 0) {
#pragma unroll
      for (int bt = 0; bt < 4; ++bt) pE1[bt * 16 + lrow][w] = s1[bt];
    }
    __syncthreads();

    float f1[4];
#pragma unroll
    for (int bt = 0; bt < 4; ++bt) {
      const float4 p = *(const float4*)pE1[bt * 16 + lrow];
      float s = p.x + p.y + p.z + p.w;
      f1[bt] = fminf(1.0f, ACLIP * rsqrtf(fmaxf(s, 1e-30f)));
    }
    float s2[4] = {0.f, 0.f, 0.f, 0.f};
#pragma unroll
    for (int ft = 0; ft < 4; ++ft)
#pragma unroll
      for (int bt = 0; bt < 4; ++bt)
#pragma unroll
        for (int r = 0; r < 4; ++r) {
          float zz = tanh_fast(acc[ft][bt][r] * f1[bt]);
          acc[ft][bt][r] = zz;
          s2[bt] += zz * zz;
        }
#pragma unroll
    for (int bt = 0; bt < 4; ++bt) {
      s2[bt] += __shfl_xor(s2[bt], 16);
      s2[bt] += __shfl_xor(s2[bt], 32);
    }
    if (lgrp == 0) {
#pragma unroll
      for (int bt = 0; bt < 4; ++bt) pE2[bt * 16 + lrow][w] = s2[bt];
    }
    __syncthreads();

#pragma unroll
    for (int bt = 0; bt < 4; ++bt) {
      const float4 p = *(const float4*)pE2[bt * 16 + lrow];
      float s = p.x + p.y + p.z + p.w;
      float f2 = fminf(1.0f, ACLIP * rsqrtf(fmaxf(s, 1e-30f)));
      int row = bt * 16 + lrow;
#pragma unroll
      for (int ft = 0; ft < 4; ++ft) {
        bf4 yv;
#pragma unroll
        for (int r = 0; r < 4; ++r) yv[r] = (__bf16)(acc[ft][bt][r] * f2);
        *(bf4*)((char*)At + row * 512 +
                (((w * 64 + ft * 16 + lgrp * 4) * 2) ^ ((row & 7) << 4))) = yv;
      }
    }
    __syncthreads();   // y visible for next stage / classifier
  }

  // ---- classifier: v = y2 @ Wc^T (16 classes), mobius epilogue ----
  // lane: batch = w*16+lrow, classes lgrp*4+r (reduce over lgrp: 2 shfls)
  float bcv[4];
#pragma unroll
  for (int r = 0; r < 4; ++r) bcv[r] = bc[lgrp * 4 + r];
  float pp = bcv[0]*bcv[0] + bcv[1]*bcv[1] + bcv[2]*bcv[2] + bcv[3]*bcv[3];
  pp += __shfl_xor(pp, 16); pp += __shfl_xor(pp, 32);
  float nb = sqrtf(fmaxf(pp, 1e-30f));
  float tnb = tanh_fast(nb);
  float pratio = (nb < 1e-4f) ? 1.0f : __fdividef(fminf(tnb, 0.999f), nb);
  float pj[4];
#pragma unroll
  for (int r = 0; r < 4; ++r) pj[r] = bcv[r] * pratio;
  float p2 = pratio * pratio * pp;

  ffrag c2 = (ffrag){0.f, 0.f, 0.f, 0.f};
#pragma unroll
  for (int ks = 0; ks < 8; ++ks) {
    bfrag a = *(const bfrag*)(Bt[0] + (ks * 64 + lane) * 8);
    bfrag b = *(const bfrag*)((const char*)At + (w * 16 + lrow) * 512 +
                              ((ks * 64 + lgrp * 16) ^ swz));
    c2 = __builtin_amdgcn_mfma_f32_16x16x32_bf16(a, b, c2, 0, 0, 0);
  }
  float g2 = c2[0]*c2[0] + c2[1]*c2[1] + c2[2]*c2[2] + c2[3]*c2[3];
  g2 += __shfl_xor(g2, 16); g2 += __shfl_xor(g2, 32);
  float gn = sqrtf(fmaxf(g2, 1e-30f));
  float tg = tanh_fast(gn);
  float rn = fminf(tg, 0.999f);
  float ratio = (gn < 1e-4f) ? 1.0f : __fdividef(rn, gn);
  float x2 = ratio * ratio * g2;
  float xj[4], r2j[4];
  float xy = 0.f;
#pragma unroll
  for (int r = 0; r < 4; ++r) { xj[r] = c2[r] * ratio; xy += xj[r] * pj[r]; }
  xy += __shfl_xor(xy, 16); xy += __shfl_xor(xy, 32);
  float na = 1.f + 2.f * xy + p2;
  float de = fmaxf(1.f + 2.f * xy + x2 * p2, 1e-15f);
  float rde = __fdividef(1.0f, de);
  float n2s = 0.f;
#pragma unroll
  for (int r = 0; r < 4; ++r) {
    r2j[r] = (na * xj[r] + (1.f - x2) * pj[r]) * rde;
    n2s += r2j[r] * r2j[r];
  }
  n2s += __shfl_xor(n2s, 16); n2s += __shfl_xor(n2s, 32);
  float n2 = sqrtf(fmaxf(n2s, 1e-30f));
  float pscl = (n2 > 0.999f) ? (0.999f / n2) : 1.0f;
  float n3 = fminf(n2, 0.999f);
  float lfac = (n3 < 1e-4f)
                   ? 1.0f
                   : __fdividef(0.5f * __logf((1.f + n3) / (1.f - n3)), n3);
  float* oT = (float*)Bt[1];   // reuse as [64][17] f32 staging (4.4 KB)
#pragma unroll
  for (int r = 0; r < 4; ++r) {
    float lg = r2j[r] * pscl * lfac;
    float sp = (lg > 20.f) ? lg : log1pf(__expf(lg));
    oT[(w * 16 + lrow) * 17 + lgrp * 4 + r] = sp;
  }
  __syncthreads();
  {
    int row = tid >> 2, c = (tid & 3) * 4;
    float4 o;
    o.x = oT[row * 17 + c];     o.y = oT[row * 17 + c + 1];
    o.z = oT[row * 17 + c + 2]; o.w = oT[row * 17 + c + 3];
    *(float4*)(out + (rowg + row) * 16 + c) = o;
  }
}

extern "C" void kernel_launch(void* const* d_in, const int* in_sizes, int n_in,
                              void* d_out, int out_size, void* d_ws, size_t ws_size,
                              hipStream_t stream) {
  (void)in_sizes; (void)n_in; (void)out_size; (void)ws_size;
  const float* x  = (const float*)d_in[0];
  const float* W1 = (const float*)d_in[1];
  const float* b1 = (const float*)d_in[2];
  const float* W2 = (const float*)d_in[3];
  const float* b2 = (const float*)d_in[4];
  const float* Wc = (const float*)d_in[5];
  const float* bc = (const float*)d_in[6];
  __bf16* wsb = (__bf16*)d_ws;          // needs 270336 B

  prep_kernel<<<66, 256, 0, stream>>>(W1, W2, Wc, wsb);
  fused_kernel<<<4096, 256, 0, stream>>>(x, b1, b2, bc, wsb, (float*)d_out);
}

// Round 12
// 176.694 us; speedup vs baseline: 1.1774x; 1.0300x over previous
//
#include <hip/hip_runtime.h>
#include <hip/hip_bf16.h>

// Fused hyperbolic MLP forward.
// Identity: logmap0(proj(expmap0(u))) == clip_norm(u, A), A = atanh(0.999).
// Classifier: res = min(tanh(||v||),0.999)*unit(v), v = z2@Wc^T (scale-exact).
// Layout: SWAPPED mfma operands -> D[feature][batch]; lane holds 16 features of
// 4 batch rows => per-row reductions are 16 local FMA + 2 shfls (x^16,x^32).
// R12: proven R11 kernel + epilogue-arithmetic-only changes (no sync/layout):
//   - all epilogue math vectorized over ffrag (float4) -> candidate v_pk_*_f32
//   - tanh via exp2 with 2*log2(e) folded into the per-row scale f1t
//   - horizontal sums once per bt instead of scalar fma folding

typedef __bf16 bfrag __attribute__((ext_vector_type(8)));   // MFMA A/B (4 VGPR)
typedef __bf16 bf4   __attribute__((ext_vector_type(4)));
typedef float  ffrag __attribute__((ext_vector_type(4)));   // MFMA C/D

#define ACLIP  3.8002012f           // atanh(0.999)
#define TSCALE 2.8853900817779268f  // 2*log2(e)

__device__ __forceinline__ float tanh_fast(float x) {
  // tanh(x) = 1 - 2/(e^{2x}+1); handles +-inf gracefully (->+-1).
  float e = __expf(2.0f * x);
  float r = __builtin_amdgcn_rcpf(e + 1.0f);
  return fmaf(-2.0f, r, 1.0f);
}
__device__ __forceinline__ float tanh_exp2(float a) {
  // a = x * 2*log2(e); returns tanh(x). exp2(+-inf) -> +-1 correctly.
  float e = __builtin_amdgcn_exp2f(a);
  float r = __builtin_amdgcn_rcpf(e + 1.0f);
  return fmaf(-2.0f, r, 1.0f);
}

// async 16B global -> LDS (DMA, no VGPR round-trip)
__device__ __forceinline__ void gl_lds16(const __bf16* g, __bf16* l) {
  __builtin_amdgcn_global_load_lds(
      (const __attribute__((address_space(1))) void*)g,
      (__attribute__((address_space(3))) void*)l, 16, 0, 0);
}
// stage one 16 KiB k-slice (1024 slots x 16B) with 256 threads: 4 issues/thread
__device__ __forceinline__ void stage_slice(const __bf16* src, __bf16* dst, int tid) {
#pragma unroll
  for (int i = 0; i < 4; ++i)
    gl_lds16(src + (i * 256 + tid) * 8, dst + (i * 256 + tid) * 8);
}
__device__ __forceinline__ void stage_wc(const __bf16* src, __bf16* dst, int tid) {
#pragma unroll
  for (int i = 0; i < 2; ++i)
    gl_lds16(src + (i * 256 + tid) * 8, dst + (i * 256 + tid) * 8);
}

// ---------------------------------------------------------------------------
// prep: reorder W1/W2/Wc (f32 [out][in]) into bf16 MFMA fragment order:
// slot(ks, nt, lane) holds W[nt*16 + (lane&15)][ks*32 + (lane>>4)*8 .. +7]
// W1 slices 0-7 (elem 0), W2 slices 8-15 (elem 65536), Wc at 131072.
// ---------------------------------------------------------------------------
__global__ void prep_kernel(const float* __restrict__ W1, const float* __restrict__ W2,
                            const float* __restrict__ Wc, __bf16* __restrict__ wsb) {
  int g = blockIdx.x * 256 + threadIdx.x;   // 0..16895
  const float* src; int s, base;
  if (g < 8192)        { src = W1; s = g;         base = 0;      }
  else if (g < 16384)  { src = W2; s = g - 8192;  base = 65536;  }
  else                 { src = Wc; s = g - 16384; base = 131072; }
  int l = s & 63, t = s >> 6;
  int nt, ks;
  if (g < 16384) { nt = t & 15; ks = t >> 4; }
  else           { nt = 0;      ks = t;      }
  int row  = nt * 16 + (l & 15);
  int col0 = ks * 32 + (l >> 4) * 8;
  bfrag v;
#pragma unroll
  for (int j = 0; j < 8; ++j) v[j] = (__bf16)src[row * 256 + col0 + j];
  *(bfrag*)(wsb + base + s * 8) = v;
}

// ---------------------------------------------------------------------------
// fused main: 64 rows/block, 4 waves; wave w owns features w*64..w*64+63 for
// all 64 batch rows (acc[ft][bt]). A-tile (X / y, bf16) XOR-swizzled in LDS;
// W double-buffered via global_load_lds (proven path), 1 barrier per k-step.
// ---------------------------------------------------------------------------
__global__ __launch_bounds__(256, 2) void fused_kernel(
    const float* __restrict__ x, const float* __restrict__ b1,
    const float* __restrict__ b2, const float* __restrict__ bc,
    const __bf16* __restrict__ wsb, float* __restrict__ out) {
  __shared__ __align__(16) __bf16 At[64 * 256];   // 32 KB, 512 B/row, swizzled
  __shared__ __align__(16) __bf16 Bt[2][8192];    // 2 x 16 KB W k-slices
  __shared__ float partX[64][4];
  __shared__ float pE1[64][4];
  __shared__ float pE2[64][4];

  const int tid  = threadIdx.x;
  const int w    = tid >> 6;
  const int lane = tid & 63;
  const int lrow = lane & 15;
  const int lgrp = lane >> 4;
  const int swz  = (lrow & 7) << 4;
  const long long rowg = (long long)blockIdx.x * 64;

  // ---- prologue: x loads (HBM) + first W slice (L2), raw bf16 At, partial norms
  float4 xv[16];
#pragma unroll
  for (int rr = 0; rr < 16; ++rr)
    xv[rr] = *(const float4*)(x + (rowg + w * 16 + rr) * 256 + lane * 4);
  stage_slice(wsb, Bt[0], tid);

  float ss[16];
#pragma unroll
  for (int rr = 0; rr < 16; ++rr) {
    int row = w * 16 + rr;
    bf4 z;
    z[0] = (__bf16)xv[rr].x; z[1] = (__bf16)xv[rr].y;
    z[2] = (__bf16)xv[rr].z; z[3] = (__bf16)xv[rr].w;
    *(bf4*)((char*)At + row * 512 + ((lane * 8) ^ ((row & 7) << 4))) = z;
    ss[rr] = xv[rr].x * xv[rr].x + xv[rr].y * xv[rr].y +
             xv[rr].z * xv[rr].z + xv[rr].w * xv[rr].w;
  }
#pragma unroll
  for (int m = 1; m <= 8; m <<= 1)
#pragma unroll
    for (int rr = 0; rr < 16; ++rr) ss[rr] += __shfl_xor(ss[rr], m);
  if (lrow == 0) {   // lanes 0,16,32,48: group-partials for the wave's 16 rows
#pragma unroll
    for (int rr = 0; rr < 16; ++rr) partX[w * 16 + rr][lgrp] = ss[rr];
  }
  __syncthreads();   // At + partX visible; Bt[0] DMA drained

  ffrag acc[4][4];   // [ft][bt]

#pragma unroll
  for (int st = 0; st < 2; ++st) {
#pragma unroll
    for (int ft = 0; ft < 4; ++ft)
#pragma unroll
      for (int bt = 0; bt < 4; ++bt) acc[ft][bt] = (ffrag){0.f, 0.f, 0.f, 0.f};

#pragma unroll
    for (int j = 0; j < 8; ++j) {
      const int t = st * 8 + j;
      if (t < 15) stage_slice(wsb + (t + 1) * 8192, Bt[(t + 1) & 1], tid);
      else        stage_wc(wsb + 131072, Bt[0], tid);   // Wc into Bt[0]
      const __bf16* cb = Bt[t & 1];
      bfrag wf[4], xf[4];
#pragma unroll
      for (int ft = 0; ft < 4; ++ft)
        wf[ft] = *(const bfrag*)(cb + ((w * 4 + ft) * 64 + lane) * 8);
#pragma unroll
      for (int bt = 0; bt < 4; ++bt)
        xf[bt] = *(const bfrag*)((const char*)At + (bt * 16 + lrow) * 512 +
                                 ((j * 64 + lgrp * 16) ^ swz));
      __builtin_amdgcn_s_setprio(1);
#pragma unroll
      for (int ft = 0; ft < 4; ++ft)
#pragma unroll
        for (int bt = 0; bt < 4; ++bt)
          acc[ft][bt] = __builtin_amdgcn_mfma_f32_16x16x32_bf16(
              wf[ft], xf[bt], acc[ft][bt], 0, 0, 0);
      __builtin_amdgcn_s_setprio(0);
      __syncthreads();   // drains next-slice DMA; protects buffer reuse
    }

    // ---- epilogue: u = f0*acc + bias; clip_norm; tanh; clip_norm; y -> At ----
    const float* bias = st ? b2 : b1;
    ffrag bbv[4];
#pragma unroll
    for (int ft = 0; ft < 4; ++ft) {
      const float4 bv = *(const float4*)(bias + w * 64 + ft * 16 + lgrp * 4);
      bbv[ft][0] = bv.x; bbv[ft][1] = bv.y; bbv[ft][2] = bv.z; bbv[ft][3] = bv.w;
    }

    float f0[4];
    if (st == 0) {
#pragma unroll
      for (int bt = 0; bt < 4; ++bt) {
        const float4 p = *(const float4*)partX[bt * 16 + lrow];
        float s = p.x + p.y + p.z + p.w;
        f0[bt] = fminf(1.0f, ACLIP * rsqrtf(fmaxf(s, 1e-30f)));
      }
    } else {
#pragma unroll
      for (int bt = 0; bt < 4; ++bt) f0[bt] = 1.0f;
    }

    ffrag s1v[4];
#pragma unroll
    for (int bt = 0; bt < 4; ++bt) s1v[bt] = (ffrag){0.f, 0.f, 0.f, 0.f};
#pragma unroll
    for (int ft = 0; ft < 4; ++ft)
#pragma unroll
      for (int bt = 0; bt < 4; ++bt) {
        ffrag u = acc[ft][bt] * f0[bt] + bbv[ft];   // vector fma (pk candidate)
        acc[ft][bt] = u;
        s1v[bt] += u * u;                           // vector fma (pk candidate)
      }
    float s1[4];
#pragma unroll
    for (int bt = 0; bt < 4; ++bt) {
      s1[bt] = (s1v[bt][0] + s1v[bt][1]) + (s1v[bt][2] + s1v[bt][3]);
      s1[bt] += __shfl_xor(s1[bt], 16);
      s1[bt] += __shfl_xor(s1[bt], 32);
    }
    if (lgrp == 0) {
#pragma unroll
      for (int bt = 0; bt < 4; ++bt) pE1[bt * 16 + lrow][w] = s1[bt];
    }
    __syncthreads();

    float f1t[4];
#pragma unroll
    for (int bt = 0; bt < 4; ++bt) {
      const float4 p = *(const float4*)pE1[bt * 16 + lrow];
      float s = p.x + p.y + p.z + p.w;
      float f1 = fminf(1.0f, ACLIP * rsqrtf(fmaxf(s, 1e-30f)));
      f1t[bt] = f1 * TSCALE;   // fold 2*log2(e) into the per-row scale
    }
    ffrag s2v[4];
#pragma unroll
    for (int bt = 0; bt < 4; ++bt) s2v[bt] = (ffrag){0.f, 0.f, 0.f, 0.f};
#pragma unroll
    for (int ft = 0; ft < 4; ++ft)
#pragma unroll
      for (int bt = 0; bt < 4; ++bt) {
        ffrag a = acc[ft][bt] * f1t[bt];            // vector mul (pk candidate)
        ffrag z;
#pragma unroll
        for (int r = 0; r < 4; ++r) z[r] = tanh_exp2(a[r]);
        acc[ft][bt] = z;
        s2v[bt] += z * z;                           // vector fma (pk candidate)
      }
    float s2[4];
#pragma unroll
    for (int bt = 0; bt < 4; ++bt) {
      s2[bt] = (s2v[bt][0] + s2v[bt][1]) + (s2v[bt][2] + s2v[bt][3]);
      s2[bt] += __shfl_xor(s2[bt], 16);
      s2[bt] += __shfl_xor(s2[bt], 32);
    }
    if (lgrp == 0) {
#pragma unroll
      for (int bt = 0; bt < 4; ++bt) pE2[bt * 16 + lrow][w] = s2[bt];
    }
    __syncthreads();

#pragma unroll
    for (int bt = 0; bt < 4; ++bt) {
      const float4 p = *(const float4*)pE2[bt * 16 + lrow];
      float s = p.x + p.y + p.z + p.w;
      float f2 = fminf(1.0f, ACLIP * rsqrtf(fmaxf(s, 1e-30f)));
      int row = bt * 16 + lrow;
#pragma unroll
      for (int ft = 0; ft < 4; ++ft) {
        ffrag y = acc[ft][bt] * f2;                 // vector mul (pk candidate)
        bf4 yv;
#pragma unroll
        for (int r = 0; r < 4; ++r) yv[r] = (__bf16)y[r];
        *(bf4*)((char*)At + row * 512 +
                (((w * 64 + ft * 16 + lgrp * 4) * 2) ^ ((row & 7) << 4))) = yv;
      }
    }
    __syncthreads();   // y visible for next stage / classifier
  }

  // ---- classifier: v = y2 @ Wc^T (16 classes), mobius epilogue ----
  // lane: batch = w*16+lrow, classes lgrp*4+r (reduce over lgrp: 2 shfls)
  float bcv[4];
#pragma unroll
  for (int r = 0; r < 4; ++r) bcv[r] = bc[lgrp * 4 + r];
  float pp = bcv[0]*bcv[0] + bcv[1]*bcv[1] + bcv[2]*bcv[2] + bcv[3]*bcv[3];
  pp += __shfl_xor(pp, 16); pp += __shfl_xor(pp, 32);
  float nb = sqrtf(fmaxf(pp, 1e-30f));
  float tnb = tanh_fast(nb);
  float pratio = (nb < 1e-4f) ? 1.0f : __fdividef(fminf(tnb, 0.999f), nb);
  float pj[4];
#pragma unroll
  for (int r = 0; r < 4; ++r) pj[r] = bcv[r] * pratio;
  float p2 = pratio * pratio * pp;

  ffrag c2 = (ffrag){0.f, 0.f, 0.f, 0.f};
#pragma unroll
  for (int ks = 0; ks < 8; ++ks) {
    bfrag a = *(const bfrag*)(Bt[0] + (ks * 64 + lane) * 8);
    bfrag b = *(const bfrag*)((const char*)At + (w * 16 + lrow) * 512 +
                              ((ks * 64 + lgrp * 16) ^ swz));
    c2 = __builtin_amdgcn_mfma_f32_16x16x32_bf16(a, b, c2, 0, 0, 0);
  }
  float g2 = c2[0]*c2[0] + c2[1]*c2[1] + c2[2]*c2[2] + c2[3]*c2[3];
  g2 += __shfl_xor(g2, 16); g2 += __shfl_xor(g2, 32);
  float gn = sqrtf(fmaxf(g2, 1e-30f));
  float tg = tanh_fast(gn);
  float rn = fminf(tg, 0.999f);
  float ratio = (gn < 1e-4f) ? 1.0f : __fdividef(rn, gn);
  float x2 = ratio * ratio * g2;
  float xj[4], r2j[4];
  float xy = 0.f;
#pragma unroll
  for (int r = 0; r < 4; ++r) { xj[r] = c2[r] * ratio; xy += xj[r] * pj[r]; }
  xy += __shfl_xor(xy, 16); xy += __shfl_xor(xy, 32);
  float na = 1.f + 2.f * xy + p2;
  float de = fmaxf(1.f + 2.f * xy + x2 * p2, 1e-15f);
  float rde = __fdividef(1.0f, de);
  float n2s = 0.f;
#pragma unroll
  for (int r = 0; r < 4; ++r) {
    r2j[r] = (na * xj[r] + (1.f - x2) * pj[r]) * rde;
    n2s += r2j[r] * r2j[r];
  }
  n2s += __shfl_xor(n2s, 16); n2s += __shfl_xor(n2s, 32);
  float n2 = sqrtf(fmaxf(n2s, 1e-30f));
  float pscl = (n2 > 0.999f) ? (0.999f / n2) : 1.0f;
  float n3 = fminf(n2, 0.999f);
  float lfac = (n3 < 1e-4f)
                   ? 1.0f
                   : __fdividef(0.5f * __logf((1.f + n3) / (1.f - n3)), n3);
  float* oT = (float*)Bt[1];   // reuse as [64][17] f32 staging (4.4 KB)
#pragma unroll
  for (int r = 0; r < 4; ++r) {
    float lg = r2j[r] * pscl * lfac;
    float sp = (lg > 20.f) ? lg : log1pf(__expf(lg));
    oT[(w * 16 + lrow) * 17 + lgrp * 4 + r] = sp;
  }
  __syncthreads();
  {
    int row = tid >> 2, c = (tid & 3) * 4;
    float4 o;
    o.x = oT[row * 17 + c];     o.y = oT[row * 17 + c + 1];
    o.z = oT[row * 17 + c + 2]; o.w = oT[row * 17 + c + 3];
    *(float4*)(out + (rowg + row) * 16 + c) = o;
  }
}

extern "C" void kernel_launch(void* const* d_in, const int* in_sizes, int n_in,
                              void* d_out, int out_size, void* d_ws, size_t ws_size,
                              hipStream_t stream) {
  (void)in_sizes; (void)n_in; (void)out_size; (void)ws_size;
  const float* x  = (const float*)d_in[0];
  const float* W1 = (const float*)d_in[1];
  const float* b1 = (const float*)d_in[2];
  const float* W2 = (const float*)d_in[3];
  const float* b2 = (const float*)d_in[4];
  const float* Wc = (const float*)d_in[5];
  const float* bc = (const float*)d_in[6];
  __bf16* wsb = (__bf16*)d_ws;          // needs 270336 B

  prep_kernel<<<66, 256, 0, stream>>>(W1, W2, Wc, wsb);
  fused_kernel<<<4096, 256, 0, stream>>>(x, b1, b2, bc, wsb, (float*)d_out);
}